// Round 15
// baseline (181.936 us; speedup 1.0000x reference)
//
#include <hip/hip_runtime.h>

typedef short bf16x8 __attribute__((ext_vector_type(8)));
typedef float floatx4 __attribute__((ext_vector_type(4)));
typedef float floatx2 __attribute__((ext_vector_type(2)));

typedef const __attribute__((address_space(1))) void* gas_ptr;
typedef __attribute__((address_space(3))) void* las_ptr;

#define EPB  2048   // edges per hist/scatter chunk (r15: was 4096; 391 chunks
                    // halve per-block serial phases + allow 2 blocks/CU)
#define MAXB 6144   // bucket capacity (mean 4081, sigma ~64 -> +32 sigma)

__device__ __forceinline__ unsigned short f2bf(float f) {
    unsigned int u = __float_as_uint(f);
    unsigned int r = u + 0x7fffu + ((u >> 16) & 1u);   // RNE
    return (unsigned short)(r >> 16);
}

// Async global->LDS 16B: HW writes lbase + lane*16; g is the per-lane source.
__device__ __forceinline__ void stage16(const void* g, void* lbase, int lane) {
#if __has_builtin(__builtin_amdgcn_global_load_lds)
    __builtin_amdgcn_global_load_lds((gas_ptr)g, (las_ptr)lbase, 16, 0, 0);
#else
    *(float4*)((char*)lbase + lane * 16) = *(const float4*)g;
#endif
}

// prep_all (1024 thr): blocks [0,nb_conv) h->bf16 8 floats/thread;
// next nblkH: hist + claim + LDS-REORDER + sequential-burst scatter into
// fixed-capacity tmp[bucket][MAXB]; last 128: weight transpose WT2[c][k].
// (r14 structure: edges reordered by bin in LDS with precomputed absolute
// destinations, then written in a linear sweep -> coalesced bursts.)
__global__ __launch_bounds__(1024) void prep_all(
    const float* __restrict__ h, unsigned short* __restrict__ hbf, int nconv8,
    const int* __restrict__ dst, const int* __restrict__ src,
    const int* __restrict__ rel, int* __restrict__ bcnt,
    unsigned int* __restrict__ tmp, int E, int nB, int nblkH,
    const float* __restrict__ basis, const float* __restrict__ loopw,
    unsigned short* __restrict__ WT2, int nb_conv)
{
    __shared__ int lh[256], scn[256], dbase[256], cur[256];   // 4 KB
    __shared__ unsigned int ebw[EPB];                         // 8 KB
    __shared__ int          eba[EPB];                         // 8 KB
    const int b = blockIdx.x;
    const int t = threadIdx.x;
    if (b < nb_conv) {
        int idx = b * 1024 + t;                // one thread = 8 floats -> 8 bf16
        if (idx < nconv8) {
            const float4 v0 = *(const float4*)(h + (size_t)idx * 8);
            const float4 v1 = *(const float4*)(h + (size_t)idx * 8 + 4);
            uint4 p;
            p.x = (unsigned int)f2bf(v0.x) | ((unsigned int)f2bf(v0.y) << 16);
            p.y = (unsigned int)f2bf(v0.z) | ((unsigned int)f2bf(v0.w) << 16);
            p.z = (unsigned int)f2bf(v1.x) | ((unsigned int)f2bf(v1.y) << 16);
            p.w = (unsigned int)f2bf(v1.z) | ((unsigned int)f2bf(v1.w) << 16);
            *(uint4*)(hbf + (size_t)idx * 8) = p;
        }
    } else if (b < nb_conv + nblkH) {
        const int blk = b - nb_conv;
        if (t < 256) lh[t] = 0;
        __syncthreads();
        const int cbase = blk * EPB;
        int dd[EPB / 1024];
#pragma unroll
        for (int j = 0; j < EPB / 1024; ++j) {
            int e = cbase + j * 1024 + t;
            dd[j] = (e < E) ? dst[e] : -1;
            if (dd[j] >= 0) atomicAdd(&lh[dd[j] >> 8], 1);
        }
        __syncthreads();
        // exclusive scan of bin counts -> lbase; claim global range per bin
        int cnt = 0;
        if (t < 256) { cnt = lh[t]; scn[t] = cnt; }
        __syncthreads();
        for (int o = 1; o < 256; o <<= 1) {
            int x = 0;
            if (t < 256 && t >= o) x = scn[t - o];
            __syncthreads();
            if (t < 256) scn[t] += x;
            __syncthreads();
        }
        if (t < 256) {
            const int lb = scn[t] - cnt;       // local exclusive base
            const int gb = cnt ? atomicAdd(&bcnt[t * 16], cnt) : 0;
            dbase[t] = t * MAXB + gb - lb;     // dest_abs = dbase[bin] + slot
            cur[t] = lb;
        }
        __syncthreads();
        // reorder into LDS by bin, recording absolute destination
#pragma unroll
        for (int j = 0; j < EPB / 1024; ++j) {
            int e = cbase + j * 1024 + t;
            int d = dd[j];
            if (d >= 0) {
                int bin = d >> 8;
                int slot = atomicAdd(&cur[bin], 1);
                ebw[slot] = (unsigned int)src[e] | ((unsigned int)rel[e] << 16)
                          | ((unsigned int)(d & 255) << 23);
                eba[slot] = dbase[bin] + slot;
            }
        }
        __syncthreads();
        // linear sweep: piecewise-sequential destinations -> coalesced bursts
        const int n4 = (E - cbase < EPB) ? (E - cbase) : EPB;
        const int lim = nB * MAXB;
        for (int i = t; i < n4; i += 1024) {
            int dsto = eba[i];
            if (dsto < lim)                    // capacity guard (unreachable)
                tmp[dsto] = ebw[i];
        }
    } else {
        int c = b - nb_conv - nblkH;            // 0..127
        if (t < 640) {
            float v;
            if (t < 512) v = basis[(size_t)t * 128 + c];
            else         v = loopw[(size_t)(t - 512) * 128 + c];
            WT2[(size_t)c * 640 + t] = f2bf(v);
        }
    }
}

// One block per bucket, 1024 threads: recompute the 196-entry bucket-base scan
// locally from bcnt (784B, L2-hot), then finish the sort by dst&255 in LDS;
// emit rowptr for the bucket's 256 dsts and the dst-sorted compact sedge
// (src<<8 | rel<<25).  (r10 version, proven)
__global__ __launch_bounds__(1024) void bucket_sort(
    const unsigned int* __restrict__ tmp, const int* __restrict__ bcnt,
    unsigned int* __restrict__ sedge, int* __restrict__ rowptr,
    int E, int N, int nB)
{
    __shared__ unsigned int eb[MAXB];
    __shared__ int hh[256], ss[256], cur[256];
    __shared__ int sbrow, scnt;
    const int b = blockIdx.x;
    const int t = threadIdx.x;

    int c = 0;
    if (t < 256) {
        c = (t < nB) ? bcnt[t * 16] : 0;
        if (c > MAXB) c = MAXB;
        ss[t] = c;
    }
    __syncthreads();
    for (int o = 1; o < 256; o <<= 1) {
        int x = 0;
        if (t < 256 && t >= o) x = ss[t - o];
        __syncthreads();
        if (t < 256) ss[t] += x;
        __syncthreads();
    }
    if (t == b) { sbrow = ss[t] - c; scnt = c; }   // b < nB <= 256
    __syncthreads();
    const int brow = sbrow;
    const int n    = scnt;

    if (t < 256) hh[t] = 0;
    __syncthreads();
    const unsigned int* tb = tmp + (size_t)b * MAXB;
    for (int i = t; i < n; i += 1024) {
        unsigned int v = tb[i];
        eb[i] = v;
        atomicAdd(&hh[(v >> 23) & 255], 1);
    }
    __syncthreads();
    int v = 0;
    if (t < 256) { v = hh[t]; ss[t] = v; }
    __syncthreads();
    for (int o = 1; o < 256; o <<= 1) {
        int x = 0;
        if (t < 256 && t >= o) x = ss[t - o];
        __syncthreads();
        if (t < 256) ss[t] += x;
        __syncthreads();
    }
    if (t < 256) {
        const int excl = ss[t] - v;
        const int idx = b * 256 + t;
        if (idx <= N) rowptr[idx] = brow + excl;   // covers rowptr[N]=E too
        cur[t] = excl;
    }
    __syncthreads();
    for (int i = t; i < n; i += 1024) {
        unsigned int e = eb[i];
        int slot = atomicAdd(&cur[(e >> 23) & 255], 1);
        sedge[brow + slot] = ((e & 0xFFFFu) << 8) | (((e >> 16) & 0x7Fu) << 25);
    }
}

// Persistent-strided gather (r11 version, measured 42.0-42.5us / 3.2TB/s —
// best of 8 variants; at its random-line traffic ceiling: 82MB fetch + 50MB
// write over ~3.2TB/s). 2048 co-resident blocks (8/CU); wave strides dsts.
__global__ __launch_bounds__(256, 8) void aggregate_pre(
    const unsigned short* __restrict__ hbf,
    const int* __restrict__ rowptr,
    const unsigned int* __restrict__ sedge,
    const float* __restrict__ coeff,
    const float* __restrict__ norm,
    unsigned short* __restrict__ A2, int N, int R)
{
    __shared__ float scoef[512];               // R*4 <= 512
    for (int i = threadIdx.x; i < R * 4; i += 256) scoef[i] = coeff[i];
    __syncthreads();

    const int wave = threadIdx.x >> 6;
    const int lane = threadIdx.x & 63;
    const int gw = blockIdx.x * 4 + wave;      // global wave id
    const int GW = gridDim.x * 4;

    const char* hbase = (const char*)hbf + lane * 4;

#define EDGE_LOAD(v, u) \
    unsigned int u = *(const unsigned int*)(hbase + ((v) & 0x00FFFF00u));
#define EDGE_MATH(v, u) { \
    const float4 c = *(const float4*)((const char*)scoef + (((v) >> 25) << 4)); \
    floatx2 hp; \
    hp[0] = __uint_as_float((u) << 16); \
    hp[1] = __uint_as_float((u) & 0xFFFF0000u); \
    a0 = __builtin_elementwise_fma((floatx2){c.x, c.x}, hp, a0); \
    a1 = __builtin_elementwise_fma((floatx2){c.y, c.y}, hp, a1); \
    a2 = __builtin_elementwise_fma((floatx2){c.z, c.z}, hp, a2); \
    a3 = __builtin_elementwise_fma((floatx2){c.w, c.w}, hp, a3); }

    for (int d = gw; d < N; d += GW) {
        int i = rowptr[d];
        const int end = rowptr[d + 1];

        floatx2 a0 = {0.f, 0.f}, a1 = {0.f, 0.f}, a2 = {0.f, 0.f}, a3 = {0.f, 0.f};

        while (i < end && (i & 3)) {
            unsigned int v = sedge[i];
            EDGE_LOAD(v, u)
            EDGE_MATH(v, u)
            ++i;
        }
        for (; i + 16 <= end; i += 16) {
            uint4 e0 = *(const uint4*)(sedge + i);
            uint4 e1 = *(const uint4*)(sedge + i + 4);
            uint4 e2 = *(const uint4*)(sedge + i + 8);
            uint4 e3 = *(const uint4*)(sedge + i + 12);
            EDGE_LOAD(e0.x, u0)  EDGE_LOAD(e0.y, u1)  EDGE_LOAD(e0.z, u2)  EDGE_LOAD(e0.w, u3)
            EDGE_LOAD(e1.x, u4)  EDGE_LOAD(e1.y, u5)  EDGE_LOAD(e1.z, u6)  EDGE_LOAD(e1.w, u7)
            EDGE_LOAD(e2.x, u8)  EDGE_LOAD(e2.y, u9)  EDGE_LOAD(e2.z, u10) EDGE_LOAD(e2.w, u11)
            EDGE_LOAD(e3.x, u12) EDGE_LOAD(e3.y, u13) EDGE_LOAD(e3.z, u14) EDGE_LOAD(e3.w, u15)
            EDGE_MATH(e0.x, u0)  EDGE_MATH(e0.y, u1)  EDGE_MATH(e0.z, u2)  EDGE_MATH(e0.w, u3)
            EDGE_MATH(e1.x, u4)  EDGE_MATH(e1.y, u5)  EDGE_MATH(e1.z, u6)  EDGE_MATH(e1.w, u7)
            EDGE_MATH(e2.x, u8)  EDGE_MATH(e2.y, u9)  EDGE_MATH(e2.z, u10) EDGE_MATH(e2.w, u11)
            EDGE_MATH(e3.x, u12) EDGE_MATH(e3.y, u13) EDGE_MATH(e3.z, u14) EDGE_MATH(e3.w, u15)
        }
        for (; i + 8 <= end; i += 8) {
            uint4 e0 = *(const uint4*)(sedge + i);
            uint4 e1 = *(const uint4*)(sedge + i + 4);
            EDGE_LOAD(e0.x, u0) EDGE_LOAD(e0.y, u1) EDGE_LOAD(e0.z, u2) EDGE_LOAD(e0.w, u3)
            EDGE_LOAD(e1.x, u4) EDGE_LOAD(e1.y, u5) EDGE_LOAD(e1.z, u6) EDGE_LOAD(e1.w, u7)
            EDGE_MATH(e0.x, u0) EDGE_MATH(e0.y, u1) EDGE_MATH(e0.z, u2) EDGE_MATH(e0.w, u3)
            EDGE_MATH(e1.x, u4) EDGE_MATH(e1.y, u5) EDGE_MATH(e1.z, u6) EDGE_MATH(e1.w, u7)
        }
        for (; i + 4 <= end; i += 4) {
            uint4 e0 = *(const uint4*)(sedge + i);
            EDGE_LOAD(e0.x, u0) EDGE_LOAD(e0.y, u1) EDGE_LOAD(e0.z, u2) EDGE_LOAD(e0.w, u3)
            EDGE_MATH(e0.x, u0) EDGE_MATH(e0.y, u1) EDGE_MATH(e0.z, u2) EDGE_MATH(e0.w, u3)
        }
        for (; i < end; ++i) {
            unsigned int v = sedge[i];
            EDGE_LOAD(v, u)
            EDGE_MATH(v, u)
        }

        const float nm = norm[d];
        unsigned short* row = A2 + (size_t)d * 512 + lane * 2;
        *(unsigned int*)(row)       = (unsigned int)f2bf(a0[0] * nm) | ((unsigned int)f2bf(a0[1] * nm) << 16);
        *(unsigned int*)(row + 128) = (unsigned int)f2bf(a1[0] * nm) | ((unsigned int)f2bf(a1[1] * nm) << 16);
        *(unsigned int*)(row + 256) = (unsigned int)f2bf(a2[0] * nm) | ((unsigned int)f2bf(a2[1] * nm) << 16);
        *(unsigned int*)(row + 384) = (unsigned int)f2bf(a3[0] * nm) | ((unsigned int)f2bf(a3[1] * nm) << 16);
    }
#undef EDGE_LOAD
#undef EDGE_MATH
}

// out = relu([A2 | h_bf] @ WT2^T): (N,640)@(640,128), LDS-tiled MFMA GEMM.
// (r10 128-row version, proven; ~14us by r8 arithmetic — at traffic floor.)
__global__ __launch_bounds__(256) void final_gemm(
    const unsigned short* __restrict__ A2,    // (N,512) bf16
    const unsigned short* __restrict__ hbf,   // (N,128) bf16
    const unsigned short* __restrict__ WT2,   // (128,640) bf16 [col][k]
    float* __restrict__ out, int N)
{
    __shared__ char sA[16384];   // [kc 0..7][row 0..127] x 16B
    __shared__ char sB[16384];   // [kc 0..7][col 0..127] x 16B
    const int t = threadIdx.x;
    const int w = t >> 6;
    const int lane = t & 63;
    const int quad = lane >> 4;
    const int low  = lane & 15;
    const int wr = w >> 1, wc = w & 1;   // 2x2 wave grid of 64x64 sub-tiles
    const int m0 = blockIdx.x * 128;

    floatx4 acc[4][4];
#pragma unroll
    for (int mt = 0; mt < 4; ++mt)
#pragma unroll
        for (int nt = 0; nt < 4; ++nt) acc[mt][nt] = (floatx4){0.f, 0.f, 0.f, 0.f};

    for (int it = 0; it < 10; ++it) {
        const int k0 = it * 64;
#pragma unroll
        for (int i = 0; i < 4; ++i) {
            const int slot = i * 256 + t;          // 0..1023
            const int kc  = slot >> 7;             // 0..7
            const int idx = slot & 127;            // row / col
            int grow = m0 + idx;
            if (grow >= N) grow = N - 1;           // clamp loads; stores guarded
            const unsigned short* gA = (k0 < 512)
                ? A2  + (size_t)grow * 512 + k0 + kc * 8
                : hbf + (size_t)grow * 128 + (k0 - 512) + kc * 8;
            const unsigned short* gB = WT2 + (size_t)idx * 640 + k0 + kc * 8;
            stage16(gA, sA + (size_t)(i * 256 + w * 64) * 16, lane);
            stage16(gB, sB + (size_t)(i * 256 + w * 64) * 16, lane);
        }
        __syncthreads();

#pragma unroll
        for (int ks = 0; ks < 2; ++ks) {
            bf16x8 af[4], bfr[4];
#pragma unroll
            for (int mt = 0; mt < 4; ++mt)
                af[mt] = *(const bf16x8*)(sA + (size_t)(((ks * 4 + quad) << 7) + wr * 64 + mt * 16 + low) * 16);
#pragma unroll
            for (int nt = 0; nt < 4; ++nt)
                bfr[nt] = *(const bf16x8*)(sB + (size_t)(((ks * 4 + quad) << 7) + wc * 64 + nt * 16 + low) * 16);
#pragma unroll
            for (int mt = 0; mt < 4; ++mt)
#pragma unroll
                for (int nt = 0; nt < 4; ++nt)
                    acc[mt][nt] = __builtin_amdgcn_mfma_f32_16x16x32_bf16(af[mt], bfr[nt], acc[mt][nt], 0, 0, 0);
        }
        __syncthreads();
    }

    // C/D: col=lane&15, row=(lane>>4)*4+reg
#pragma unroll
    for (int mt = 0; mt < 4; ++mt) {
#pragma unroll
        for (int nt = 0; nt < 4; ++nt) {
            const int c = wc * 64 + nt * 16 + low;
#pragma unroll
            for (int r = 0; r < 4; ++r) {
                int rr = m0 + wr * 64 + mt * 16 + quad * 4 + r;
                if (rr < N) out[(size_t)rr * 128 + c] = fmaxf(acc[mt][nt][r], 0.f);
            }
        }
    }
}

extern "C" void kernel_launch(void* const* d_in, const int* in_sizes, int n_in,
                              void* d_out, int out_size, void* d_ws, size_t ws_size,
                              hipStream_t stream)
{
    const float* h     = (const float*)d_in[0];
    const float* norm  = (const float*)d_in[1];
    const int*   src   = (const int*)d_in[2];
    const int*   dst   = (const int*)d_in[3];
    const int*   rel   = (const int*)d_in[4];
    const float* basis = (const float*)d_in[5];
    const float* coeff = (const float*)d_in[6];
    const float* loopw = (const float*)d_in[7];
    float* out = (float*)d_out;

    const int N = in_sizes[1];       // 50000
    const int E = in_sizes[2];       // 800000
    const int R = in_sizes[6] / 4;   // 100

    const int nB    = (N + 255) >> 8;              // 196 coarse buckets (256 dsts)
    const int nblkH = (E + EPB - 1) / EPB;         // 391 edge chunks

    char* ws = (char*)d_ws;
    size_t off = 0;
    auto walloc = [&](size_t bytes) -> char* {
        char* p = ws + off;
        off = (off + bytes + 255) & ~(size_t)255;
        return p;
    };
    unsigned short* A2     = (unsigned short*)walloc((size_t)N * 512 * 2);  // 51.2 MB
    unsigned short* hbf    = (unsigned short*)walloc((size_t)N * 128 * 2);  // 12.8 MB
    unsigned short* WT2    = (unsigned short*)walloc(128 * 640 * 2);
    int*            rowptr = (int*)walloc((size_t)(N + 1) * 4);
    int*            bcnt   = (int*)walloc((size_t)nB * 16 * 4);   // 64B-padded counters
    unsigned int*   tmp    = (unsigned int*)walloc((size_t)nB * MAXB * 4);  // 4.8 MB
    unsigned int*   sedge  = (unsigned int*)walloc((size_t)E * 4);

    const int nconv8  = N * 16;                    // 8 floats per thread
    const int nb_conv = (nconv8 + 1023) / 1024;    // 782

    hipMemsetAsync(bcnt, 0, (size_t)nB * 16 * 4, stream);
    prep_all<<<nb_conv + nblkH + 128, 1024, 0, stream>>>(
        h, hbf, nconv8, dst, src, rel, bcnt, tmp, E, nB, nblkH,
        basis, loopw, WT2, nb_conv);
    bucket_sort<<<nB, 1024, 0, stream>>>(tmp, bcnt, sedge, rowptr, E, N, nB);
    aggregate_pre<<<2048, 256, 0, stream>>>(hbf, rowptr, sedge, coeff, norm, A2, N, R);
    final_gemm<<<(N + 127) / 128, 256, 0, stream>>>(A2, hbf, WT2, out, N);
}

// Round 16
// 177.862 us; speedup vs baseline: 1.0229x; 1.0229x over previous
//
#include <hip/hip_runtime.h>

typedef short bf16x8 __attribute__((ext_vector_type(8)));
typedef float floatx4 __attribute__((ext_vector_type(4)));
typedef float floatx2 __attribute__((ext_vector_type(2)));

typedef const __attribute__((address_space(1))) void* gas_ptr;
typedef __attribute__((address_space(3))) void* las_ptr;

#define EPB  4096   // edges per hist/scatter chunk (r14 proven; r15's 2048 regressed)
#define MAXB 6144   // bucket capacity (mean 4081, sigma ~64 -> +32 sigma)

__device__ __forceinline__ unsigned short f2bf(float f) {
    unsigned int u = __float_as_uint(f);
    unsigned int r = u + 0x7fffu + ((u >> 16) & 1u);   // RNE
    return (unsigned short)(r >> 16);
}

// Async global->LDS 16B: HW writes lbase + lane*16; g is the per-lane source.
__device__ __forceinline__ void stage16(const void* g, void* lbase, int lane) {
#if __has_builtin(__builtin_amdgcn_global_load_lds)
    __builtin_amdgcn_global_load_lds((gas_ptr)g, (las_ptr)lbase, 16, 0, 0);
#else
    *(float4*)((char*)lbase + lane * 16) = *(const float4*)g;
#endif
}

// prep_all (1024 thr): blocks [0,nb_conv) h->bf16 8 floats/thread;
// next nblkH: hist + claim + LDS-REORDER + sequential-burst scatter into
// fixed-capacity tmp[bucket][MAXB]; last 128: weight transpose WT2[c][k].
// (r14 version, proven: LDS reorder made tmp stores piecewise-sequential.)
__global__ __launch_bounds__(1024) void prep_all(
    const float* __restrict__ h, unsigned short* __restrict__ hbf, int nconv8,
    const int* __restrict__ dst, const int* __restrict__ src,
    const int* __restrict__ rel, int* __restrict__ bcnt,
    unsigned int* __restrict__ tmp, int E, int nB, int nblkH,
    const float* __restrict__ basis, const float* __restrict__ loopw,
    unsigned short* __restrict__ WT2, int nb_conv)
{
    __shared__ int lh[256], scn[256], dbase[256], cur[256];   // 4 KB
    __shared__ unsigned int ebw[EPB];                         // 16 KB
    __shared__ int          eba[EPB];                         // 16 KB
    const int b = blockIdx.x;
    const int t = threadIdx.x;
    if (b < nb_conv) {
        int idx = b * 1024 + t;                // one thread = 8 floats -> 8 bf16
        if (idx < nconv8) {
            const float4 v0 = *(const float4*)(h + (size_t)idx * 8);
            const float4 v1 = *(const float4*)(h + (size_t)idx * 8 + 4);
            uint4 p;
            p.x = (unsigned int)f2bf(v0.x) | ((unsigned int)f2bf(v0.y) << 16);
            p.y = (unsigned int)f2bf(v0.z) | ((unsigned int)f2bf(v0.w) << 16);
            p.z = (unsigned int)f2bf(v1.x) | ((unsigned int)f2bf(v1.y) << 16);
            p.w = (unsigned int)f2bf(v1.z) | ((unsigned int)f2bf(v1.w) << 16);
            *(uint4*)(hbf + (size_t)idx * 8) = p;
        }
    } else if (b < nb_conv + nblkH) {
        const int blk = b - nb_conv;
        if (t < 256) lh[t] = 0;
        __syncthreads();
        const int cbase = blk * EPB;
        int dd[EPB / 1024];
#pragma unroll
        for (int j = 0; j < EPB / 1024; ++j) {
            int e = cbase + j * 1024 + t;
            dd[j] = (e < E) ? dst[e] : -1;
            if (dd[j] >= 0) atomicAdd(&lh[dd[j] >> 8], 1);
        }
        __syncthreads();
        // exclusive scan of bin counts -> lbase; claim global range per bin
        int cnt = 0;
        if (t < 256) { cnt = lh[t]; scn[t] = cnt; }
        __syncthreads();
        for (int o = 1; o < 256; o <<= 1) {
            int x = 0;
            if (t < 256 && t >= o) x = scn[t - o];
            __syncthreads();
            if (t < 256) scn[t] += x;
            __syncthreads();
        }
        if (t < 256) {
            const int lb = scn[t] - cnt;       // local exclusive base
            const int gb = cnt ? atomicAdd(&bcnt[t * 16], cnt) : 0;
            dbase[t] = t * MAXB + gb - lb;     // dest_abs = dbase[bin] + slot
            cur[t] = lb;
        }
        __syncthreads();
        // reorder into LDS by bin, recording absolute destination
#pragma unroll
        for (int j = 0; j < EPB / 1024; ++j) {
            int e = cbase + j * 1024 + t;
            int d = dd[j];
            if (d >= 0) {
                int bin = d >> 8;
                int slot = atomicAdd(&cur[bin], 1);
                ebw[slot] = (unsigned int)src[e] | ((unsigned int)rel[e] << 16)
                          | ((unsigned int)(d & 255) << 23);
                eba[slot] = dbase[bin] + slot;
            }
        }
        __syncthreads();
        // linear sweep: piecewise-sequential destinations -> coalesced bursts
        const int n4 = (E - cbase < EPB) ? (E - cbase) : EPB;
        const int lim = nB * MAXB;
        for (int i = t; i < n4; i += 1024) {
            int dsto = eba[i];
            if (dsto < lim)                    // capacity guard (unreachable)
                tmp[dsto] = ebw[i];
        }
    } else {
        int c = b - nb_conv - nblkH;            // 0..127
        if (t < 640) {
            float v;
            if (t < 512) v = basis[(size_t)t * 128 + c];
            else         v = loopw[(size_t)(t - 512) * 128 + c];
            WT2[(size_t)c * 640 + t] = f2bf(v);
        }
    }
}

// One block per bucket, 1024 threads: local bucket-base scan from bcnt, sort
// by dst&255 in LDS, emit rowptr + dst-sorted sedge (src<<8 | rel<<25).
// R16 change: the sedge scatter previously wrote via per-dst LDS cursors ->
// each wave store touched up to 64 lines across the bucket's 16KB window
// (~4x writeback amplification, same pathology r14 fixed in prep). Since the
// sorted positions are a permutation of [0,n), reorder into LDS (ebw[slot])
// then write sedge[brow+i] = ebw[i] in a perfectly coalesced linear sweep.
__global__ __launch_bounds__(1024) void bucket_sort(
    const unsigned int* __restrict__ tmp, const int* __restrict__ bcnt,
    unsigned int* __restrict__ sedge, int* __restrict__ rowptr,
    int E, int N, int nB)
{
    __shared__ unsigned int eb[MAXB];          // 24 KB
    __shared__ unsigned int ebw[MAXB];         // 24 KB (sorted staging)
    __shared__ int hh[256], ss[256], cur[256];
    __shared__ int sbrow, scnt;
    const int b = blockIdx.x;
    const int t = threadIdx.x;

    int c = 0;
    if (t < 256) {
        c = (t < nB) ? bcnt[t * 16] : 0;
        if (c > MAXB) c = MAXB;
        ss[t] = c;
    }
    __syncthreads();
    for (int o = 1; o < 256; o <<= 1) {
        int x = 0;
        if (t < 256 && t >= o) x = ss[t - o];
        __syncthreads();
        if (t < 256) ss[t] += x;
        __syncthreads();
    }
    if (t == b) { sbrow = ss[t] - c; scnt = c; }   // b < nB <= 256
    __syncthreads();
    const int brow = sbrow;
    const int n    = scnt;

    if (t < 256) hh[t] = 0;
    __syncthreads();
    const unsigned int* tb = tmp + (size_t)b * MAXB;
    for (int i = t; i < n; i += 1024) {
        unsigned int v = tb[i];
        eb[i] = v;
        atomicAdd(&hh[(v >> 23) & 255], 1);
    }
    __syncthreads();
    int v = 0;
    if (t < 256) { v = hh[t]; ss[t] = v; }
    __syncthreads();
    for (int o = 1; o < 256; o <<= 1) {
        int x = 0;
        if (t < 256 && t >= o) x = ss[t - o];
        __syncthreads();
        if (t < 256) ss[t] += x;
        __syncthreads();
    }
    if (t < 256) {
        const int excl = ss[t] - v;
        const int idx = b * 256 + t;
        if (idx <= N) rowptr[idx] = brow + excl;   // covers rowptr[N]=E too
        cur[t] = excl;
    }
    __syncthreads();
    // sort into LDS staging (slot is a permutation of [0,n))
    for (int i = t; i < n; i += 1024) {
        unsigned int e = eb[i];
        int slot = atomicAdd(&cur[(e >> 23) & 255], 1);
        ebw[slot] = ((e & 0xFFFFu) << 8) | (((e >> 16) & 0x7Fu) << 25);
    }
    __syncthreads();
    // coalesced linear sweep to global
    for (int i = t; i < n; i += 1024)
        sedge[brow + i] = ebw[i];
}

// Persistent-strided gather (r11 version, measured 42.0-42.5us / 3.2TB/s —
// best of 8 variants; at its random-line traffic ceiling: 82MB fetch + 50MB
// write over ~3.2TB/s). 2048 co-resident blocks (8/CU); wave strides dsts.
__global__ __launch_bounds__(256, 8) void aggregate_pre(
    const unsigned short* __restrict__ hbf,
    const int* __restrict__ rowptr,
    const unsigned int* __restrict__ sedge,
    const float* __restrict__ coeff,
    const float* __restrict__ norm,
    unsigned short* __restrict__ A2, int N, int R)
{
    __shared__ float scoef[512];               // R*4 <= 512
    for (int i = threadIdx.x; i < R * 4; i += 256) scoef[i] = coeff[i];
    __syncthreads();

    const int wave = threadIdx.x >> 6;
    const int lane = threadIdx.x & 63;
    const int gw = blockIdx.x * 4 + wave;      // global wave id
    const int GW = gridDim.x * 4;

    const char* hbase = (const char*)hbf + lane * 4;

#define EDGE_LOAD(v, u) \
    unsigned int u = *(const unsigned int*)(hbase + ((v) & 0x00FFFF00u));
#define EDGE_MATH(v, u) { \
    const float4 c = *(const float4*)((const char*)scoef + (((v) >> 25) << 4)); \
    floatx2 hp; \
    hp[0] = __uint_as_float((u) << 16); \
    hp[1] = __uint_as_float((u) & 0xFFFF0000u); \
    a0 = __builtin_elementwise_fma((floatx2){c.x, c.x}, hp, a0); \
    a1 = __builtin_elementwise_fma((floatx2){c.y, c.y}, hp, a1); \
    a2 = __builtin_elementwise_fma((floatx2){c.z, c.z}, hp, a2); \
    a3 = __builtin_elementwise_fma((floatx2){c.w, c.w}, hp, a3); }

    for (int d = gw; d < N; d += GW) {
        int i = rowptr[d];
        const int end = rowptr[d + 1];

        floatx2 a0 = {0.f, 0.f}, a1 = {0.f, 0.f}, a2 = {0.f, 0.f}, a3 = {0.f, 0.f};

        while (i < end && (i & 3)) {
            unsigned int v = sedge[i];
            EDGE_LOAD(v, u)
            EDGE_MATH(v, u)
            ++i;
        }
        for (; i + 16 <= end; i += 16) {
            uint4 e0 = *(const uint4*)(sedge + i);
            uint4 e1 = *(const uint4*)(sedge + i + 4);
            uint4 e2 = *(const uint4*)(sedge + i + 8);
            uint4 e3 = *(const uint4*)(sedge + i + 12);
            EDGE_LOAD(e0.x, u0)  EDGE_LOAD(e0.y, u1)  EDGE_LOAD(e0.z, u2)  EDGE_LOAD(e0.w, u3)
            EDGE_LOAD(e1.x, u4)  EDGE_LOAD(e1.y, u5)  EDGE_LOAD(e1.z, u6)  EDGE_LOAD(e1.w, u7)
            EDGE_LOAD(e2.x, u8)  EDGE_LOAD(e2.y, u9)  EDGE_LOAD(e2.z, u10) EDGE_LOAD(e2.w, u11)
            EDGE_LOAD(e3.x, u12) EDGE_LOAD(e3.y, u13) EDGE_LOAD(e3.z, u14) EDGE_LOAD(e3.w, u15)
            EDGE_MATH(e0.x, u0)  EDGE_MATH(e0.y, u1)  EDGE_MATH(e0.z, u2)  EDGE_MATH(e0.w, u3)
            EDGE_MATH(e1.x, u4)  EDGE_MATH(e1.y, u5)  EDGE_MATH(e1.z, u6)  EDGE_MATH(e1.w, u7)
            EDGE_MATH(e2.x, u8)  EDGE_MATH(e2.y, u9)  EDGE_MATH(e2.z, u10) EDGE_MATH(e2.w, u11)
            EDGE_MATH(e3.x, u12) EDGE_MATH(e3.y, u13) EDGE_MATH(e3.z, u14) EDGE_MATH(e3.w, u15)
        }
        for (; i + 8 <= end; i += 8) {
            uint4 e0 = *(const uint4*)(sedge + i);
            uint4 e1 = *(const uint4*)(sedge + i + 4);
            EDGE_LOAD(e0.x, u0) EDGE_LOAD(e0.y, u1) EDGE_LOAD(e0.z, u2) EDGE_LOAD(e0.w, u3)
            EDGE_LOAD(e1.x, u4) EDGE_LOAD(e1.y, u5) EDGE_LOAD(e1.z, u6) EDGE_LOAD(e1.w, u7)
            EDGE_MATH(e0.x, u0) EDGE_MATH(e0.y, u1) EDGE_MATH(e0.z, u2) EDGE_MATH(e0.w, u3)
            EDGE_MATH(e1.x, u4) EDGE_MATH(e1.y, u5) EDGE_MATH(e1.z, u6) EDGE_MATH(e1.w, u7)
        }
        for (; i + 4 <= end; i += 4) {
            uint4 e0 = *(const uint4*)(sedge + i);
            EDGE_LOAD(e0.x, u0) EDGE_LOAD(e0.y, u1) EDGE_LOAD(e0.z, u2) EDGE_LOAD(e0.w, u3)
            EDGE_MATH(e0.x, u0) EDGE_MATH(e0.y, u1) EDGE_MATH(e0.z, u2) EDGE_MATH(e0.w, u3)
        }
        for (; i < end; ++i) {
            unsigned int v = sedge[i];
            EDGE_LOAD(v, u)
            EDGE_MATH(v, u)
        }

        const float nm = norm[d];
        unsigned short* row = A2 + (size_t)d * 512 + lane * 2;
        *(unsigned int*)(row)       = (unsigned int)f2bf(a0[0] * nm) | ((unsigned int)f2bf(a0[1] * nm) << 16);
        *(unsigned int*)(row + 128) = (unsigned int)f2bf(a1[0] * nm) | ((unsigned int)f2bf(a1[1] * nm) << 16);
        *(unsigned int*)(row + 256) = (unsigned int)f2bf(a2[0] * nm) | ((unsigned int)f2bf(a2[1] * nm) << 16);
        *(unsigned int*)(row + 384) = (unsigned int)f2bf(a3[0] * nm) | ((unsigned int)f2bf(a3[1] * nm) << 16);
    }
#undef EDGE_LOAD
#undef EDGE_MATH
}

// out = relu([A2 | h_bf] @ WT2^T): (N,640)@(640,128), LDS-tiled MFMA GEMM.
// (r10 128-row version, proven; ~14us by r8 arithmetic — at traffic floor.)
__global__ __launch_bounds__(256) void final_gemm(
    const unsigned short* __restrict__ A2,    // (N,512) bf16
    const unsigned short* __restrict__ hbf,   // (N,128) bf16
    const unsigned short* __restrict__ WT2,   // (128,640) bf16 [col][k]
    float* __restrict__ out, int N)
{
    __shared__ char sA[16384];   // [kc 0..7][row 0..127] x 16B
    __shared__ char sB[16384];   // [kc 0..7][col 0..127] x 16B
    const int t = threadIdx.x;
    const int w = t >> 6;
    const int lane = t & 63;
    const int quad = lane >> 4;
    const int low  = lane & 15;
    const int wr = w >> 1, wc = w & 1;   // 2x2 wave grid of 64x64 sub-tiles
    const int m0 = blockIdx.x * 128;

    floatx4 acc[4][4];
#pragma unroll
    for (int mt = 0; mt < 4; ++mt)
#pragma unroll
        for (int nt = 0; nt < 4; ++nt) acc[mt][nt] = (floatx4){0.f, 0.f, 0.f, 0.f};

    for (int it = 0; it < 10; ++it) {
        const int k0 = it * 64;
#pragma unroll
        for (int i = 0; i < 4; ++i) {
            const int slot = i * 256 + t;          // 0..1023
            const int kc  = slot >> 7;             // 0..7
            const int idx = slot & 127;            // row / col
            int grow = m0 + idx;
            if (grow >= N) grow = N - 1;           // clamp loads; stores guarded
            const unsigned short* gA = (k0 < 512)
                ? A2  + (size_t)grow * 512 + k0 + kc * 8
                : hbf + (size_t)grow * 128 + (k0 - 512) + kc * 8;
            const unsigned short* gB = WT2 + (size_t)idx * 640 + k0 + kc * 8;
            stage16(gA, sA + (size_t)(i * 256 + w * 64) * 16, lane);
            stage16(gB, sB + (size_t)(i * 256 + w * 64) * 16, lane);
        }
        __syncthreads();

#pragma unroll
        for (int ks = 0; ks < 2; ++ks) {
            bf16x8 af[4], bfr[4];
#pragma unroll
            for (int mt = 0; mt < 4; ++mt)
                af[mt] = *(const bf16x8*)(sA + (size_t)(((ks * 4 + quad) << 7) + wr * 64 + mt * 16 + low) * 16);
#pragma unroll
            for (int nt = 0; nt < 4; ++nt)
                bfr[nt] = *(const bf16x8*)(sB + (size_t)(((ks * 4 + quad) << 7) + wc * 64 + nt * 16 + low) * 16);
#pragma unroll
            for (int mt = 0; mt < 4; ++mt)
#pragma unroll
                for (int nt = 0; nt < 4; ++nt)
                    acc[mt][nt] = __builtin_amdgcn_mfma_f32_16x16x32_bf16(af[mt], bfr[nt], acc[mt][nt], 0, 0, 0);
        }
        __syncthreads();
    }

    // C/D: col=lane&15, row=(lane>>4)*4+reg
#pragma unroll
    for (int mt = 0; mt < 4; ++mt) {
#pragma unroll
        for (int nt = 0; nt < 4; ++nt) {
            const int c = wc * 64 + nt * 16 + low;
#pragma unroll
            for (int r = 0; r < 4; ++r) {
                int rr = m0 + wr * 64 + mt * 16 + quad * 4 + r;
                if (rr < N) out[(size_t)rr * 128 + c] = fmaxf(acc[mt][nt][r], 0.f);
            }
        }
    }
}

extern "C" void kernel_launch(void* const* d_in, const int* in_sizes, int n_in,
                              void* d_out, int out_size, void* d_ws, size_t ws_size,
                              hipStream_t stream)
{
    const float* h     = (const float*)d_in[0];
    const float* norm  = (const float*)d_in[1];
    const int*   src   = (const int*)d_in[2];
    const int*   dst   = (const int*)d_in[3];
    const int*   rel   = (const int*)d_in[4];
    const float* basis = (const float*)d_in[5];
    const float* coeff = (const float*)d_in[6];
    const float* loopw = (const float*)d_in[7];
    float* out = (float*)d_out;

    const int N = in_sizes[1];       // 50000
    const int E = in_sizes[2];       // 800000
    const int R = in_sizes[6] / 4;   // 100

    const int nB    = (N + 255) >> 8;              // 196 coarse buckets (256 dsts)
    const int nblkH = (E + EPB - 1) / EPB;         // 196 edge chunks

    char* ws = (char*)d_ws;
    size_t off = 0;
    auto walloc = [&](size_t bytes) -> char* {
        char* p = ws + off;
        off = (off + bytes + 255) & ~(size_t)255;
        return p;
    };
    unsigned short* A2     = (unsigned short*)walloc((size_t)N * 512 * 2);  // 51.2 MB
    unsigned short* hbf    = (unsigned short*)walloc((size_t)N * 128 * 2);  // 12.8 MB
    unsigned short* WT2    = (unsigned short*)walloc(128 * 640 * 2);
    int*            rowptr = (int*)walloc((size_t)(N + 1) * 4);
    int*            bcnt   = (int*)walloc((size_t)nB * 16 * 4);   // 64B-padded counters
    unsigned int*   tmp    = (unsigned int*)walloc((size_t)nB * MAXB * 4);  // 4.8 MB
    unsigned int*   sedge  = (unsigned int*)walloc((size_t)E * 4);

    const int nconv8  = N * 16;                    // 8 floats per thread
    const int nb_conv = (nconv8 + 1023) / 1024;    // 782

    hipMemsetAsync(bcnt, 0, (size_t)nB * 16 * 4, stream);
    prep_all<<<nb_conv + nblkH + 128, 1024, 0, stream>>>(
        h, hbf, nconv8, dst, src, rel, bcnt, tmp, E, nB, nblkH,
        basis, loopw, WT2, nb_conv);
    bucket_sort<<<nB, 1024, 0, stream>>>(tmp, bcnt, sedge, rowptr, E, N, nB);
    aggregate_pre<<<2048, 256, 0, stream>>>(hbf, rowptr, sedge, coeff, norm, A2, N, R);
    final_gemm<<<(N + 127) / 128, 256, 0, stream>>>(A2, hbf, WT2, out, N);
}